// Round 5
// baseline (660.352 us; speedup 1.0000x reference)
//
#include <hip/hip_runtime.h>
#include <float.h>

// MemN2N: B=128, M=200, S=20, Q=20, H=3 hops, V=50000, D=128
// Inputs: story int32 [B,M,S], query int32 [B,Q], E f32 [4,V,D], T f32 [4,M,D]
// Output (FP32): ahat [B,V] ++ softmax(ahat) [B,V]
// All math fp32 (R4: bf16 LDS tile caused absmax 0.25 > 0.11 threshold).
// ws_size-branched: msum-in-ws fast path if ws fits 52.5 MB, else fused path.
// fp32 u[128][128] staged at head of second output half (dead until softmax).

constexpr int Bn = 128;
constexpr int Mn = 200;
constexpr int Sn = 20;
constexpr int Qn = 20;
constexpr int Hn = 3;
constexpr int Vn = 50000;
constexpr int Dn = 128;
constexpr int CH = 100;   // fused-path chunk rows (fp32 tile 100x128 = 51.2 KB)

constexpr size_t MSUM_ELEMS = (size_t)(Hn + 1) * Bn * Mn * Dn;  // 13,107,200

// ===========================================================================
// PATH 1 (workspace): msum[t][b][m][d] = sum_s E[t][story[b][m][s]][d] + T[t][m][d]
// ===========================================================================
__global__ __launch_bounds__(128)
void msum_kernel(const int* __restrict__ story, const float* __restrict__ E,
                 const float* __restrict__ T, float* __restrict__ msum) {
    int row = blockIdx.x;                 // t*B*M + b*M + m
    int t   = row / (Bn * Mn);
    int rem = row - t * (Bn * Mn);
    int b   = rem / Mn;
    int m   = rem - b * Mn;
    int d   = threadIdx.x;

    const int* st = story + (b * Mn + m) * Sn;
    float acc = T[(t * Mn + m) * Dn + d];
    #pragma unroll
    for (int s = 0; s < Sn; ++s)
        acc += E[((size_t)t * Vn + (size_t)st[s]) * Dn + d];
    msum[(size_t)row * Dn + d] = acc;
}

// Per-batch hop chain from precomputed fp32 msum. grid = B x 256 (4 waves).
__global__ __launch_bounds__(256)
void hops_kernel(const int* __restrict__ query, const float* __restrict__ E,
                 const float* __restrict__ msum, float* __restrict__ ufin) {
    __shared__ float u[Dn];
    __shared__ float sc[Mn];
    __shared__ float op[2 * Dn];
    __shared__ float red[8];
    __shared__ float bc[2];

    int b    = blockIdx.x;
    int tid  = threadIdx.x;
    int wave = tid >> 6;
    int lane = tid & 63;

    if (tid < Dn) {
        float acc = 0.f;
        const int* q = query + b * Qn;
        #pragma unroll
        for (int j = 0; j < Qn; ++j)
            acc += E[(size_t)q[j] * Dn + tid];
        u[tid] = acc;
    }
    __syncthreads();

    for (int hop = 0; hop < Hn; ++hop) {
        const float* mrow = msum + ((size_t)hop * Bn + b) * (size_t)(Mn * Dn);
        for (int m = wave * 50; m < wave * 50 + 50; ++m) {
            const float* r = mrow + m * Dn;
            float p = r[lane] * u[lane] + r[lane + 64] * u[lane + 64];
            #pragma unroll
            for (int off = 32; off; off >>= 1) p += __shfl_down(p, off, 64);
            if (lane == 0) sc[m] = p;
        }
        __syncthreads();

        float v = (tid < Mn) ? sc[tid] : -FLT_MAX;
        float mx = v;
        #pragma unroll
        for (int off = 32; off; off >>= 1) mx = fmaxf(mx, __shfl_down(mx, off, 64));
        if (lane == 0) red[wave] = mx;
        __syncthreads();
        if (tid == 0) bc[0] = fmaxf(fmaxf(red[0], red[1]), fmaxf(red[2], red[3]));
        __syncthreads();
        float rmax = bc[0];
        float e = (tid < Mn) ? expf(v - rmax) : 0.f;
        float sm = e;
        #pragma unroll
        for (int off = 32; off; off >>= 1) sm += __shfl_down(sm, off, 64);
        if (lane == 0) red[4 + wave] = sm;
        __syncthreads();
        if (tid == 0) bc[1] = red[4] + red[5] + red[6] + red[7];
        __syncthreads();
        float inv = 1.f / bc[1];
        if (tid < Mn) sc[tid] = e * inv;
        __syncthreads();

        const float* crow = msum + ((size_t)(hop + 1) * Bn + b) * (size_t)(Mn * Dn);
        int d    = tid & (Dn - 1);
        int half = tid >> 7;
        float acc = 0.f;
        for (int m = half * 100; m < half * 100 + 100; ++m)
            acc += sc[m] * crow[m * Dn + d];
        op[half * Dn + d] = acc;
        __syncthreads();
        if (tid < Dn) u[tid] += op[tid] + op[Dn + tid];
        __syncthreads();
    }
    if (tid < Dn) ufin[b * Dn + tid] = u[tid];
}

// ===========================================================================
// PATH 2 (no workspace): fused hops, fp32 LDS tile chunked 2 x 100 rows.
// One block per b, 1024 threads (16 waves). Resident-chunk reuse: the c-phase
// of hop h ends with (table h+1, chunk1) in LDS, which is the m-tile chunk1
// of hop h+1 -> skip that build.
// ===========================================================================
__global__ __launch_bounds__(1024)
void hops_fused_kernel(const int* __restrict__ story, const int* __restrict__ query,
                       const float* __restrict__ E, const float* __restrict__ T,
                       float* __restrict__ ufin) {
    __shared__ float tile[CH * Dn];   // 51,200 B
    __shared__ float u[Dn];
    __shared__ float sc[Mn];
    __shared__ float op[8 * Dn];
    __shared__ float red[16];
    __shared__ float bc[2];

    const int b    = blockIdx.x;
    const int tid  = threadIdx.x;
    const int wave = tid >> 6;
    const int lane = tid & 63;
    const int d    = tid & (Dn - 1);
    const int g    = tid >> 7;                 // 8 row-groups
    const int* st  = story + b * (Mn * Sn);

    // u0 = sum_q E[0][query[b][q]]  (visible after first build's sync)
    if (tid < Dn) {
        float acc = 0.f;
        const int* q = query + b * Qn;
        #pragma unroll
        for (int j = 0; j < Qn; ++j)
            acc += E[(size_t)q[j] * Dn + tid];
        u[tid] = acc;
    }

    auto build = [&](int t, int base) {
        const float* Et = E + (size_t)t * Vn * Dn;
        const float* Tt = T + (size_t)t * Mn * Dn;
        for (int m = base + g; m < base + CH; m += 8) {
            const int* sm = st + m * Sn;
            float acc = Tt[m * Dn + d];
            #pragma unroll
            for (int s = 0; s < Sn; ++s)
                acc += Et[(size_t)sm[s] * Dn + d];
            tile[(m - base) * Dn + d] = acc;
        }
    };
    auto scores = [&](int base) {
        for (int m = base + wave; m < base + CH; m += 16) {
            float p = tile[(m - base) * Dn + lane]      * u[lane]
                    + tile[(m - base) * Dn + lane + 64] * u[lane + 64];
            #pragma unroll
            for (int off = 32; off; off >>= 1) p += __shfl_down(p, off, 64);
            if (lane == 0) sc[m] = p;
        }
    };

    for (int hop = 0; hop < Hn; ++hop) {
        // ---- m-phase: table `hop`
        if (hop == 0) {
            build(0, 0);  __syncthreads(); scores(0);  __syncthreads();
            build(0, CH); __syncthreads(); scores(CH); __syncthreads();
        } else {
            scores(CH); __syncthreads();               // resident (hop, chunk1)
            build(hop, 0); __syncthreads(); scores(0); __syncthreads();
        }

        // ---- softmax over sc[0..200)
        float v = (tid < Mn) ? sc[tid] : -FLT_MAX;
        float mx = v;
        #pragma unroll
        for (int off = 32; off; off >>= 1) mx = fmaxf(mx, __shfl_down(mx, off, 64));
        if (lane == 0) red[wave] = mx;
        __syncthreads();
        if (tid == 0) {
            float m0 = red[0];
            #pragma unroll
            for (int i = 1; i < 16; ++i) m0 = fmaxf(m0, red[i]);
            bc[0] = m0;
        }
        __syncthreads();
        float rmax = bc[0];
        float e = (tid < Mn) ? expf(v - rmax) : 0.f;
        float sm = e;
        #pragma unroll
        for (int off = 32; off; off >>= 1) sm += __shfl_down(sm, off, 64);
        if (lane == 0) red[wave] = sm;
        __syncthreads();
        if (tid == 0) {
            float s = 0.f;
            #pragma unroll
            for (int i = 0; i < 16; ++i) s += red[i];
            bc[1] = s;
        }
        __syncthreads();
        float inv = 1.f / bc[1];
        if (tid < Mn) sc[tid] = e * inv;   // visible after next build's sync

        // ---- c-phase: table hop+1, accumulate o in a register
        float oacc = 0.f;
        build(hop + 1, 0);
        __syncthreads();
        for (int m = g; m < CH; m += 8)
            oacc += sc[m] * tile[m * Dn + d];
        __syncthreads();
        build(hop + 1, CH);
        __syncthreads();
        for (int m = CH + g; m < 2 * CH; m += 8)
            oacc += sc[m] * tile[(m - CH) * Dn + d];
        op[g * Dn + d] = oacc;
        __syncthreads();
        if (tid < Dn) {
            float s = 0.f;
            #pragma unroll
            for (int i = 0; i < 8; ++i) s += op[i * Dn + tid];
            u[tid] += s;
        }
        __syncthreads();
    }

    if (tid < Dn) ufin[b * Dn + tid] = u[tid];
}

// ===========================================================================
// Kernel: ahat[b][v] = dot(u[b], E3[v]) fp32. Pair layout b=tid>>1, dh=tid&1,
// 64 u floats in VGPRs, halves combined via shfl_xor(1). grid ceil(V/64) x 256.
// ===========================================================================
__global__ __launch_bounds__(256)
void ahat_kernel(const float* __restrict__ E, const float* __restrict__ ufin,
                 float* __restrict__ out) {
    __shared__ float res[Bn * 65];        // pad 64->65: conflict-free
    const float* E3 = E + (size_t)Hn * Vn * Dn;

    int tid = threadIdx.x;
    int b   = tid >> 1;
    int dh  = tid & 1;

    float4 ur[16];
    const float4* up = (const float4*)(ufin + b * Dn + dh * 64);
    #pragma unroll
    for (int j = 0; j < 16; ++j) ur[j] = up[j];

    int vbase = blockIdx.x * 64;
    int nv = Vn - vbase; if (nv > 64) nv = 64;

    for (int vi = 0; vi < nv; ++vi) {
        int v = vbase + vi;
        const float4* e4 = (const float4*)(E3 + (size_t)v * Dn + dh * 64);
        float acc = 0.f;
        #pragma unroll
        for (int j = 0; j < 16; ++j) {
            float4 ev = e4[j];
            acc += ur[j].x * ev.x + ur[j].y * ev.y + ur[j].z * ev.z + ur[j].w * ev.w;
        }
        acc += __shfl_xor(acc, 1, 64);
        if (dh == 0) res[b * 65 + vi] = acc;
    }
    __syncthreads();

    for (int i = tid; i < Bn * 64; i += 256) {
        int bb = i >> 6, vv = i & 63;
        if (vv < nv)
            out[(size_t)bb * Vn + vbase + vv] = res[bb * 65 + vv];
    }
}

// ===========================================================================
// Kernel: row softmax over V=50000 (fp32). grid = B x 1024.
// ===========================================================================
__global__ __launch_bounds__(1024)
void softmax_kernel(const float* __restrict__ ahat, float* __restrict__ osm) {
    __shared__ float red[16];
    __shared__ float bc;

    int b    = blockIdx.x;
    int tid  = threadIdx.x;
    int wave = tid >> 6;
    int lane = tid & 63;

    const float* row  = ahat + (size_t)b * Vn;
    float*       orow = osm  + (size_t)b * Vn;

    float mx = -FLT_MAX;
    for (int v = tid; v < Vn; v += 1024)
        mx = fmaxf(mx, row[v]);
    #pragma unroll
    for (int off = 32; off; off >>= 1) mx = fmaxf(mx, __shfl_down(mx, off, 64));
    if (lane == 0) red[wave] = mx;
    __syncthreads();
    if (tid == 0) {
        float m = red[0];
        #pragma unroll
        for (int i = 1; i < 16; ++i) m = fmaxf(m, red[i]);
        bc = m;
    }
    __syncthreads();
    float rmax = bc;

    float sum = 0.f;
    for (int v = tid; v < Vn; v += 1024)
        sum += expf(row[v] - rmax);
    #pragma unroll
    for (int off = 32; off; off >>= 1) sum += __shfl_down(sum, off, 64);
    if (lane == 0) red[wave] = sum;
    __syncthreads();
    if (tid == 0) {
        float s = 0.f;
        #pragma unroll
        for (int i = 0; i < 16; ++i) s += red[i];
        bc = s;
    }
    __syncthreads();
    float inv = 1.f / bc;

    for (int v = tid; v < Vn; v += 1024)
        orow[v] = expf(row[v] - rmax) * inv;
}

// ===========================================================================
extern "C" void kernel_launch(void* const* d_in, const int* in_sizes, int n_in,
                              void* d_out, int out_size, void* d_ws, size_t ws_size,
                              hipStream_t stream) {
    const int*   story = (const int*)d_in[0];
    const int*   query = (const int*)d_in[1];
    const float* E     = (const float*)d_in[2];
    const float* T     = (const float*)d_in[3];

    float* out  = (float*)d_out;
    float* ufin = out + (size_t)Bn * Vn;   // staged in dead second output half

    if (ws_size >= MSUM_ELEMS * sizeof(float)) {
        float* msum = (float*)d_ws;
        msum_kernel<<<(Hn + 1) * Bn * Mn, 128, 0, stream>>>(story, E, T, msum);
        hops_kernel<<<Bn, 256, 0, stream>>>(query, E, msum, ufin);
    } else {
        hops_fused_kernel<<<Bn, 1024, 0, stream>>>(story, query, E, T, ufin);
    }
    ahat_kernel<<<(Vn + 63) / 64, 256, 0, stream>>>(E, ufin, out);
    softmax_kernel<<<Bn, 1024, 0, stream>>>(out, out + (size_t)Bn * Vn);
}

// Round 6
// 437.548 us; speedup vs baseline: 1.5092x; 1.5092x over previous
//
#include <hip/hip_runtime.h>
#include <float.h>

// MemN2N: B=128, M=200, S=20, Q=20, H=3 hops, V=50000, D=128
// Inputs: story int32 [B,M,S], query int32 [B,Q], E f32 [4,V,D], T f32 [4,M,D]
// Output (FP32): ahat [B,V] ++ softmax(ahat) [B,V]
// ws_size-branched: msum-in-ws fast path if ws fits 52.5 MB, else fused path.
// fp32 u[128][128] staged at head of second output half (dead until softmax).

constexpr int Bn = 128;
constexpr int Mn = 200;
constexpr int Sn = 20;
constexpr int Qn = 20;
constexpr int Hn = 3;
constexpr int Vn = 50000;
constexpr int Dn = 128;
constexpr int CH = 100;   // fused-path chunk rows (fp32 tile 100x128 = 51.2 KB)

constexpr size_t MSUM_ELEMS = (size_t)(Hn + 1) * Bn * Mn * Dn;  // 13,107,200

// ===========================================================================
// PATH 1 (workspace): msum[t][b][m][d] = sum_s E[t][story[b][m][s]][d] + T[t][m][d]
// float4 per thread, 32 lanes per row-slot, 8 slots per 256-thread block.
// Same s-ascending add order as before -> bit-identical msum.
// ===========================================================================
__global__ __launch_bounds__(256)
void msum_kernel(const int* __restrict__ story, const float* __restrict__ E,
                 const float* __restrict__ T, float* __restrict__ msum) {
    int slot = threadIdx.x >> 5;          // 0..7
    int l    = threadIdx.x & 31;          // float4 index within row
    int row  = blockIdx.x * 8 + slot;     // t*B*M + b*M + m   (total 102,400)
    int t    = row / (Bn * Mn);
    int rem  = row - t * (Bn * Mn);
    int b    = rem / Mn;
    int m    = rem - b * Mn;

    const int* st = story + (b * Mn + m) * Sn;
    const float4* Tv = (const float4*)(T) + (size_t)(t * Mn + m) * 32;
    const float4* Et = (const float4*)(E) + (size_t)t * Vn * 32;

    float4 acc = Tv[l];
    #pragma unroll
    for (int s = 0; s < Sn; ++s) {
        float4 e = Et[(size_t)st[s] * 32 + l];
        acc.x += e.x; acc.y += e.y; acc.z += e.z; acc.w += e.w;
    }
    ((float4*)msum)[(size_t)row * 32 + l] = acc;
}

// Per-batch hop chain from precomputed fp32 msum. grid = B x 256 (4 waves).
__global__ __launch_bounds__(256)
void hops_kernel(const int* __restrict__ query, const float* __restrict__ E,
                 const float* __restrict__ msum, float* __restrict__ ufin) {
    __shared__ float u[Dn];
    __shared__ float sc[Mn];
    __shared__ float op[2 * Dn];
    __shared__ float red[8];
    __shared__ float bc[2];

    int b    = blockIdx.x;
    int tid  = threadIdx.x;
    int wave = tid >> 6;
    int lane = tid & 63;

    if (tid < Dn) {
        float acc = 0.f;
        const int* q = query + b * Qn;
        #pragma unroll
        for (int j = 0; j < Qn; ++j)
            acc += E[(size_t)q[j] * Dn + tid];
        u[tid] = acc;
    }
    __syncthreads();

    for (int hop = 0; hop < Hn; ++hop) {
        const float* mrow = msum + ((size_t)hop * Bn + b) * (size_t)(Mn * Dn);
        for (int m = wave * 50; m < wave * 50 + 50; ++m) {
            const float* r = mrow + m * Dn;
            float p = r[lane] * u[lane] + r[lane + 64] * u[lane + 64];
            #pragma unroll
            for (int off = 32; off; off >>= 1) p += __shfl_down(p, off, 64);
            if (lane == 0) sc[m] = p;
        }
        __syncthreads();

        float v = (tid < Mn) ? sc[tid] : -FLT_MAX;
        float mx = v;
        #pragma unroll
        for (int off = 32; off; off >>= 1) mx = fmaxf(mx, __shfl_down(mx, off, 64));
        if (lane == 0) red[wave] = mx;
        __syncthreads();
        if (tid == 0) bc[0] = fmaxf(fmaxf(red[0], red[1]), fmaxf(red[2], red[3]));
        __syncthreads();
        float rmax = bc[0];
        float e = (tid < Mn) ? expf(v - rmax) : 0.f;
        float sm = e;
        #pragma unroll
        for (int off = 32; off; off >>= 1) sm += __shfl_down(sm, off, 64);
        if (lane == 0) red[4 + wave] = sm;
        __syncthreads();
        if (tid == 0) bc[1] = red[4] + red[5] + red[6] + red[7];
        __syncthreads();
        float inv = 1.f / bc[1];
        if (tid < Mn) sc[tid] = e * inv;
        __syncthreads();

        const float* crow = msum + ((size_t)(hop + 1) * Bn + b) * (size_t)(Mn * Dn);
        int d    = tid & (Dn - 1);
        int half = tid >> 7;
        float acc = 0.f;
        for (int m = half * 100; m < half * 100 + 100; ++m)
            acc += sc[m] * crow[m * Dn + d];
        op[half * Dn + d] = acc;
        __syncthreads();
        if (tid < Dn) u[tid] += op[tid] + op[Dn + tid];
        __syncthreads();
    }
    if (tid < Dn) ufin[b * Dn + tid] = u[tid];
}

// ===========================================================================
// PATH 2 (no workspace): fused hops, fp32 LDS tile chunked 2 x 100 rows.
// One block per b, 1024 threads (16 waves). Build loops float4-vectorized
// (32 lanes per row-slot, 32 slots). Same add order -> identical numerics.
// ===========================================================================
__global__ __launch_bounds__(1024)
void hops_fused_kernel(const int* __restrict__ story, const int* __restrict__ query,
                       const float* __restrict__ E, const float* __restrict__ T,
                       float* __restrict__ ufin) {
    __shared__ __align__(16) float tile[CH * Dn];   // 51,200 B
    __shared__ float u[Dn];
    __shared__ float sc[Mn];
    __shared__ float op[8 * Dn];
    __shared__ float red[16];
    __shared__ float bc[2];

    const int b    = blockIdx.x;
    const int tid  = threadIdx.x;
    const int wave = tid >> 6;
    const int lane = tid & 63;
    const int d    = tid & (Dn - 1);
    const int g    = tid >> 7;                 // 8 row-groups (c-phase)
    const int slot = tid >> 5;                 // 32 row-slots (build)
    const int l    = tid & 31;                 // float4 idx (build)
    const int* st  = story + b * (Mn * Sn);

    // u0 = sum_q E[0][query[b][q]]  (visible after first build's sync)
    if (tid < Dn) {
        float acc = 0.f;
        const int* q = query + b * Qn;
        #pragma unroll
        for (int j = 0; j < Qn; ++j)
            acc += E[(size_t)q[j] * Dn + tid];
        u[tid] = acc;
    }

    auto build = [&](int t, int base) {
        const float4* Et = (const float4*)(E) + (size_t)t * Vn * 32;
        const float4* Tt = (const float4*)(T) + (size_t)t * Mn * 32;
        for (int m = base + slot; m < base + CH; m += 32) {
            const int* sm = st + m * Sn;
            float4 acc = Tt[(size_t)m * 32 + l];
            #pragma unroll
            for (int s = 0; s < Sn; ++s) {
                float4 e = Et[(size_t)sm[s] * 32 + l];
                acc.x += e.x; acc.y += e.y; acc.z += e.z; acc.w += e.w;
            }
            ((float4*)tile)[(m - base) * 32 + l] = acc;
        }
    };
    auto scores = [&](int base) {
        for (int m = base + wave; m < base + CH; m += 16) {
            float p = tile[(m - base) * Dn + lane]      * u[lane]
                    + tile[(m - base) * Dn + lane + 64] * u[lane + 64];
            #pragma unroll
            for (int off = 32; off; off >>= 1) p += __shfl_down(p, off, 64);
            if (lane == 0) sc[m] = p;
        }
    };

    for (int hop = 0; hop < Hn; ++hop) {
        // ---- m-phase: table `hop`
        if (hop == 0) {
            build(0, 0);  __syncthreads(); scores(0);  __syncthreads();
            build(0, CH); __syncthreads(); scores(CH); __syncthreads();
        } else {
            scores(CH); __syncthreads();               // resident (hop, chunk1)
            build(hop, 0); __syncthreads(); scores(0); __syncthreads();
        }

        // ---- softmax over sc[0..200)
        float v = (tid < Mn) ? sc[tid] : -FLT_MAX;
        float mx = v;
        #pragma unroll
        for (int off = 32; off; off >>= 1) mx = fmaxf(mx, __shfl_down(mx, off, 64));
        if (lane == 0) red[wave] = mx;
        __syncthreads();
        if (tid == 0) {
            float m0 = red[0];
            #pragma unroll
            for (int i = 1; i < 16; ++i) m0 = fmaxf(m0, red[i]);
            bc[0] = m0;
        }
        __syncthreads();
        float rmax = bc[0];
        float e = (tid < Mn) ? expf(v - rmax) : 0.f;
        float sm = e;
        #pragma unroll
        for (int off = 32; off; off >>= 1) sm += __shfl_down(sm, off, 64);
        if (lane == 0) red[wave] = sm;
        __syncthreads();
        if (tid == 0) {
            float s = 0.f;
            #pragma unroll
            for (int i = 0; i < 16; ++i) s += red[i];
            bc[1] = s;
        }
        __syncthreads();
        float inv = 1.f / bc[1];
        if (tid < Mn) sc[tid] = e * inv;   // visible after next build's sync

        // ---- c-phase: table hop+1, accumulate o in a register
        float oacc = 0.f;
        build(hop + 1, 0);
        __syncthreads();
        for (int m = g; m < CH; m += 8)
            oacc += sc[m] * tile[m * Dn + d];
        __syncthreads();
        build(hop + 1, CH);
        __syncthreads();
        for (int m = CH + g; m < 2 * CH; m += 8)
            oacc += sc[m] * tile[(m - CH) * Dn + d];
        op[g * Dn + d] = oacc;
        __syncthreads();
        if (tid < Dn) {
            float s = 0.f;
            #pragma unroll
            for (int i = 0; i < 8; ++i) s += op[i * Dn + tid];
            u[tid] += s;
        }
        __syncthreads();
    }

    if (tid < Dn) ufin[b * Dn + tid] = u[tid];
}

// ===========================================================================
// ahat GEMM: C[b,v] = sum_d U[b,d]*E3[v,d].  M=128, N=50000, K=128.
// Block: 128b x 128v tile, 256 threads (16 tr x 16 tc), 8x8 acc/thread.
// K staged in 32-chunks through LDS, transposed [k][col] with gap layout
// col' = col + 4*(col>>5), row stride 140: b128 fragment reads are 2-way
// (free, m136); staging writes 4-way (rare). k-order ascending -> bit-
// identical to R5's serial dot. LDS 2x17.9 KB -> 4 blocks/CU.
// ===========================================================================
constexpr int KC   = 32;
constexpr int LSTR = 140;
__device__ __forceinline__ int ldsCol(int c) { return c + 4 * (c >> 5); }

__global__ __launch_bounds__(256)
void ahat_gemm_kernel(const float* __restrict__ E, const float* __restrict__ ufin,
                      float* __restrict__ out) {
    __shared__ float uA[KC * LSTR];
    __shared__ float eB[KC * LSTR];
    const float* E3 = E + (size_t)Hn * Vn * Dn;

    const int tid   = threadIdx.x;
    const int tr    = tid & 15;
    const int tc    = tid >> 4;
    const int vbase = blockIdx.x * 128;

    const int f4 = tid & 7;        // k-float4 within chunk
    const int rr = tid >> 3;       // staging row 0..31 (+32 per iter)

    float acc[8][8];
    #pragma unroll
    for (int i = 0; i < 8; ++i)
        #pragma unroll
        for (int j = 0; j < 8; ++j) acc[i][j] = 0.f;

    for (int kb = 0; kb < Dn; kb += KC) {
        #pragma unroll
        for (int i = 0; i < 4; ++i) {
            int r  = rr + 32 * i;
            float4 uv = *(const float4*)(ufin + (size_t)r * Dn + kb + f4 * 4);
            int vg = vbase + r; if (vg > Vn - 1) vg = Vn - 1;
            float4 ev = *(const float4*)(E3 + (size_t)vg * Dn + kb + f4 * 4);
            int col = ldsCol(r);
            uA[(f4 * 4 + 0) * LSTR + col] = uv.x;
            uA[(f4 * 4 + 1) * LSTR + col] = uv.y;
            uA[(f4 * 4 + 2) * LSTR + col] = uv.z;
            uA[(f4 * 4 + 3) * LSTR + col] = uv.w;
            eB[(f4 * 4 + 0) * LSTR + col] = ev.x;
            eB[(f4 * 4 + 1) * LSTR + col] = ev.y;
            eB[(f4 * 4 + 2) * LSTR + col] = ev.z;
            eB[(f4 * 4 + 3) * LSTR + col] = ev.w;
        }
        __syncthreads();
        const int ca = ldsCol(tr * 8);
        const int cb = ldsCol(tc * 8);
        #pragma unroll 4
        for (int k = 0; k < KC; ++k) {
            float4 a0 = *(const float4*)&uA[k * LSTR + ca];
            float4 a1 = *(const float4*)&uA[k * LSTR + ca + 4];
            float4 b0 = *(const float4*)&eB[k * LSTR + cb];
            float4 b1 = *(const float4*)&eB[k * LSTR + cb + 4];
            float av[8] = {a0.x, a0.y, a0.z, a0.w, a1.x, a1.y, a1.z, a1.w};
            float bv[8] = {b0.x, b0.y, b0.z, b0.w, b1.x, b1.y, b1.z, b1.w};
            #pragma unroll
            for (int i = 0; i < 8; ++i)
                #pragma unroll
                for (int j = 0; j < 8; ++j)
                    acc[i][j] += av[i] * bv[j];
        }
        __syncthreads();
    }

    if (vbase + tc * 8 < Vn) {        // last tile: valid width 80 = 10*8
        #pragma unroll
        for (int i = 0; i < 8; ++i) {
            int bb = tr * 8 + i;
            float* p = out + (size_t)bb * Vn + vbase + tc * 8;
            *(float4*)(p)     = make_float4(acc[i][0], acc[i][1], acc[i][2], acc[i][3]);
            *(float4*)(p + 4) = make_float4(acc[i][4], acc[i][5], acc[i][6], acc[i][7]);
        }
    }
}

// ===========================================================================
// Row softmax over V=50000 (fp32), float4-vectorized (50000 = 12500*4).
// grid = B x 1024.
// ===========================================================================
__global__ __launch_bounds__(1024)
void softmax_kernel(const float* __restrict__ ahat, float* __restrict__ osm) {
    __shared__ float red[16];
    __shared__ float bc;

    int b    = blockIdx.x;
    int tid  = threadIdx.x;
    int wave = tid >> 6;
    int lane = tid & 63;

    const float4* row  = (const float4*)(ahat + (size_t)b * Vn);
    float4*       orow = (float4*)(osm + (size_t)b * Vn);
    constexpr int N4 = Vn / 4;     // 12500

    float mx = -FLT_MAX;
    for (int v = tid; v < N4; v += 1024) {
        float4 x = row[v];
        mx = fmaxf(mx, fmaxf(fmaxf(x.x, x.y), fmaxf(x.z, x.w)));
    }
    #pragma unroll
    for (int off = 32; off; off >>= 1) mx = fmaxf(mx, __shfl_down(mx, off, 64));
    if (lane == 0) red[wave] = mx;
    __syncthreads();
    if (tid == 0) {
        float m = red[0];
        #pragma unroll
        for (int i = 1; i < 16; ++i) m = fmaxf(m, red[i]);
        bc = m;
    }
    __syncthreads();
    float rmax = bc;

    float sum = 0.f;
    for (int v = tid; v < N4; v += 1024) {
        float4 x = row[v];
        sum += expf(x.x - rmax) + expf(x.y - rmax) + expf(x.z - rmax) + expf(x.w - rmax);
    }
    #pragma unroll
    for (int off = 32; off; off >>= 1) sum += __shfl_down(sum, off, 64);
    if (lane == 0) red[wave] = sum;
    __syncthreads();
    if (tid == 0) {
        float s = 0.f;
        #pragma unroll
        for (int i = 0; i < 16; ++i) s += red[i];
        bc = s;
    }
    __syncthreads();
    float inv = 1.f / bc;

    for (int v = tid; v < N4; v += 1024) {
        float4 x = row[v];
        orow[v] = make_float4(expf(x.x - rmax) * inv, expf(x.y - rmax) * inv,
                              expf(x.z - rmax) * inv, expf(x.w - rmax) * inv);
    }
}

// ===========================================================================
extern "C" void kernel_launch(void* const* d_in, const int* in_sizes, int n_in,
                              void* d_out, int out_size, void* d_ws, size_t ws_size,
                              hipStream_t stream) {
    const int*   story = (const int*)d_in[0];
    const int*   query = (const int*)d_in[1];
    const float* E     = (const float*)d_in[2];
    const float* T     = (const float*)d_in[3];

    float* out  = (float*)d_out;
    float* ufin = out + (size_t)Bn * Vn;   // staged in dead second output half

    if (ws_size >= MSUM_ELEMS * sizeof(float)) {
        float* msum = (float*)d_ws;
        msum_kernel<<<(Hn + 1) * Bn * Mn / 8, 256, 0, stream>>>(story, E, T, msum);
        hops_kernel<<<Bn, 256, 0, stream>>>(query, E, msum, ufin);
    } else {
        hops_fused_kernel<<<Bn, 1024, 0, stream>>>(story, query, E, T, ufin);
    }
    ahat_gemm_kernel<<<(Vn + 127) / 128, 256, 0, stream>>>(E, ufin, out);
    softmax_kernel<<<Bn, 1024, 0, stream>>>(out, out + (size_t)Bn * Vn);
}

// Round 7
// 351.448 us; speedup vs baseline: 1.8789x; 1.2450x over previous
//
#include <hip/hip_runtime.h>
#include <float.h>

// MemN2N: B=128, M=200, S=20, Q=20, H=3 hops, V=50000, D=128
// Inputs: story int32 [B,M,S], query int32 [B,Q], E f32 [4,V,D], T f32 [4,M,D]
// Output (FP32): ahat [B,V] ++ softmax(ahat) [B,V]
// ws path: msum 52.5 MB in d_ws (taken — R6 profile shows msum_kernel).
// fp32 u[128][128] staged at head of second output half (dead until softmax).

constexpr int Bn = 128;
constexpr int Mn = 200;
constexpr int Sn = 20;
constexpr int Qn = 20;
constexpr int Hn = 3;
constexpr int Vn = 50000;
constexpr int Dn = 128;
constexpr int CH = 100;   // fused-path chunk rows

constexpr size_t MSUM_ELEMS = (size_t)(Hn + 1) * Bn * Mn * Dn;  // 13,107,200

// ===========================================================================
// PATH 1: msum[t][b][m][d] = sum_s E[t][story[b][m][s]][d] + T[t][m][d]
// float4/thread, 32 lanes per row-slot, 8 slots per 256-thread block.
// ===========================================================================
__global__ __launch_bounds__(256)
void msum_kernel(const int* __restrict__ story, const float* __restrict__ E,
                 const float* __restrict__ T, float* __restrict__ msum) {
    int slot = threadIdx.x >> 5;          // 0..7
    int l    = threadIdx.x & 31;          // float4 index within row
    int row  = blockIdx.x * 8 + slot;     // t*B*M + b*M + m   (total 102,400)
    int t    = row / (Bn * Mn);
    int rem  = row - t * (Bn * Mn);
    int b    = rem / Mn;
    int m    = rem - b * Mn;

    const int* st = story + (b * Mn + m) * Sn;
    const float4* Tv = (const float4*)(T) + (size_t)(t * Mn + m) * 32;
    const float4* Et = (const float4*)(E) + (size_t)t * Vn * 32;

    float4 acc = Tv[l];
    #pragma unroll
    for (int s = 0; s < Sn; ++s) {
        float4 e = Et[(size_t)st[s] * 32 + l];
        acc.x += e.x; acc.y += e.y; acc.z += e.z; acc.w += e.w;
    }
    ((float4*)msum)[(size_t)row * 32 + l] = acc;
}

// ===========================================================================
// Hop chain from msum. grid = B x 1024 (16 waves).
// Score phase: each wave reduces TWO independent m-rows per iteration (ILP).
// c-phase: 8 groups x 128 d, 25 coalesced loads each.
// ===========================================================================
__global__ __launch_bounds__(1024)
void hops_kernel(const int* __restrict__ query, const float* __restrict__ E,
                 const float* __restrict__ msum, float* __restrict__ ufin) {
    __shared__ float u[Dn];
    __shared__ float sc[Mn];
    __shared__ float op[8 * Dn];
    __shared__ float red[16];
    __shared__ float bc[2];

    const int b    = blockIdx.x;
    const int tid  = threadIdx.x;
    const int wave = tid >> 6;
    const int lane = tid & 63;
    const int d    = tid & (Dn - 1);
    const int g    = tid >> 7;             // 0..7

    if (tid < Dn) {
        float acc = 0.f;
        const int* q = query + b * Qn;
        #pragma unroll
        for (int j = 0; j < Qn; ++j)
            acc += E[(size_t)q[j] * Dn + tid];
        u[tid] = acc;
    }
    __syncthreads();

    for (int hop = 0; hop < Hn; ++hop) {
        const float* mrow = msum + ((size_t)hop * Bn + b) * (size_t)(Mn * Dn);
        float ul = u[lane], uh = u[lane + 64];

        // scores: wave handles pairs (2*mm, 2*mm+1), mm = wave, wave+16, ...
        for (int mm = wave; mm < Mn / 2; mm += 16) {
            const float* r0 = mrow + (2 * mm) * Dn;
            const float* r1 = r0 + Dn;
            float p0 = r0[lane] * ul + r0[lane + 64] * uh;
            float p1 = r1[lane] * ul + r1[lane + 64] * uh;
            #pragma unroll
            for (int off = 32; off; off >>= 1) {
                p0 += __shfl_down(p0, off, 64);
                p1 += __shfl_down(p1, off, 64);
            }
            if (lane == 0) { sc[2 * mm] = p0; sc[2 * mm + 1] = p1; }
        }
        __syncthreads();

        // softmax over sc[0..200)
        float v = (tid < Mn) ? sc[tid] : -FLT_MAX;
        float mx = v;
        #pragma unroll
        for (int off = 32; off; off >>= 1) mx = fmaxf(mx, __shfl_down(mx, off, 64));
        if (lane == 0) red[wave] = mx;
        __syncthreads();
        if (tid == 0) {
            float m0 = red[0];
            #pragma unroll
            for (int i = 1; i < 16; ++i) m0 = fmaxf(m0, red[i]);
            bc[0] = m0;
        }
        __syncthreads();
        float rmax = bc[0];
        float e = (tid < Mn) ? expf(v - rmax) : 0.f;
        float sm = e;
        #pragma unroll
        for (int off = 32; off; off >>= 1) sm += __shfl_down(sm, off, 64);
        if (lane == 0) red[wave] = sm;
        __syncthreads();
        if (tid == 0) {
            float s = 0.f;
            #pragma unroll
            for (int i = 0; i < 16; ++i) s += red[i];
            bc[1] = s;
        }
        __syncthreads();
        float inv = 1.f / bc[1];
        if (tid < Mn) sc[tid] = e * inv;
        __syncthreads();

        // o[d] = sum_m proba[m] * c[m][d]; u += o
        const float* crow = msum + ((size_t)(hop + 1) * Bn + b) * (size_t)(Mn * Dn);
        float acc = 0.f;
        for (int m = g; m < Mn; m += 8)
            acc += sc[m] * crow[m * Dn + d];
        op[g * Dn + d] = acc;
        __syncthreads();
        if (tid < Dn) {
            float s = 0.f;
            #pragma unroll
            for (int i = 0; i < 8; ++i) s += op[i * Dn + tid];
            u[tid] += s;
        }
        __syncthreads();
    }
    if (tid < Dn) ufin[b * Dn + tid] = u[tid];
}

// ===========================================================================
// PATH 2 (no workspace, fallback): fused hops — unchanged from R6.
// ===========================================================================
__global__ __launch_bounds__(1024)
void hops_fused_kernel(const int* __restrict__ story, const int* __restrict__ query,
                       const float* __restrict__ E, const float* __restrict__ T,
                       float* __restrict__ ufin) {
    __shared__ __align__(16) float tile[CH * Dn];
    __shared__ float u[Dn];
    __shared__ float sc[Mn];
    __shared__ float op[8 * Dn];
    __shared__ float red[16];
    __shared__ float bc[2];

    const int b    = blockIdx.x;
    const int tid  = threadIdx.x;
    const int wave = tid >> 6;
    const int lane = tid & 63;
    const int d    = tid & (Dn - 1);
    const int g    = tid >> 7;
    const int slot = tid >> 5;
    const int l    = tid & 31;
    const int* st  = story + b * (Mn * Sn);

    if (tid < Dn) {
        float acc = 0.f;
        const int* q = query + b * Qn;
        #pragma unroll
        for (int j = 0; j < Qn; ++j)
            acc += E[(size_t)q[j] * Dn + tid];
        u[tid] = acc;
    }

    auto build = [&](int t, int base) {
        const float4* Et = (const float4*)(E) + (size_t)t * Vn * 32;
        const float4* Tt = (const float4*)(T) + (size_t)t * Mn * 32;
        for (int m = base + slot; m < base + CH; m += 32) {
            const int* sm = st + m * Sn;
            float4 acc = Tt[(size_t)m * 32 + l];
            #pragma unroll
            for (int s = 0; s < Sn; ++s) {
                float4 e = Et[(size_t)sm[s] * 32 + l];
                acc.x += e.x; acc.y += e.y; acc.z += e.z; acc.w += e.w;
            }
            ((float4*)tile)[(m - base) * 32 + l] = acc;
        }
    };
    auto scores = [&](int base) {
        for (int m = base + wave; m < base + CH; m += 16) {
            float p = tile[(m - base) * Dn + lane]      * u[lane]
                    + tile[(m - base) * Dn + lane + 64] * u[lane + 64];
            #pragma unroll
            for (int off = 32; off; off >>= 1) p += __shfl_down(p, off, 64);
            if (lane == 0) sc[m] = p;
        }
    };

    for (int hop = 0; hop < Hn; ++hop) {
        if (hop == 0) {
            build(0, 0);  __syncthreads(); scores(0);  __syncthreads();
            build(0, CH); __syncthreads(); scores(CH); __syncthreads();
        } else {
            scores(CH); __syncthreads();
            build(hop, 0); __syncthreads(); scores(0); __syncthreads();
        }

        float v = (tid < Mn) ? sc[tid] : -FLT_MAX;
        float mx = v;
        #pragma unroll
        for (int off = 32; off; off >>= 1) mx = fmaxf(mx, __shfl_down(mx, off, 64));
        if (lane == 0) red[wave] = mx;
        __syncthreads();
        if (tid == 0) {
            float m0 = red[0];
            #pragma unroll
            for (int i = 1; i < 16; ++i) m0 = fmaxf(m0, red[i]);
            bc[0] = m0;
        }
        __syncthreads();
        float rmax = bc[0];
        float e = (tid < Mn) ? expf(v - rmax) : 0.f;
        float sm = e;
        #pragma unroll
        for (int off = 32; off; off >>= 1) sm += __shfl_down(sm, off, 64);
        if (lane == 0) red[wave] = sm;
        __syncthreads();
        if (tid == 0) {
            float s = 0.f;
            #pragma unroll
            for (int i = 0; i < 16; ++i) s += red[i];
            bc[1] = s;
        }
        __syncthreads();
        float inv = 1.f / bc[1];
        if (tid < Mn) sc[tid] = e * inv;

        float oacc = 0.f;
        build(hop + 1, 0);
        __syncthreads();
        for (int m = g; m < CH; m += 8)
            oacc += sc[m] * tile[m * Dn + d];
        __syncthreads();
        build(hop + 1, CH);
        __syncthreads();
        for (int m = CH + g; m < 2 * CH; m += 8)
            oacc += sc[m] * tile[(m - CH) * Dn + d];
        op[g * Dn + d] = oacc;
        __syncthreads();
        if (tid < Dn) {
            float s = 0.f;
            #pragma unroll
            for (int i = 0; i < 8; ++i) s += op[i * Dn + tid];
            u[tid] += s;
        }
        __syncthreads();
    }

    if (tid < Dn) ufin[b * Dn + tid] = u[tid];
}

// ===========================================================================
// ahat GEMM: C[b,v] = sum_d U[b,d]*E3[v,d].  M=128, N=50000, K=128.
// Tile 128b x 64v (782 blocks -> ~3/CU), 256 threads (16 tr x 16 tc),
// 8x4 acc/thread. K in 32-chunks through LDS, transposed [k][col] with gap
// layout col' = col + 4*(col>>5): fragment b128 reads 2-way (free, m136).
// ===========================================================================
constexpr int KC    = 32;
constexpr int LSTRA = 140;   // 128 cols + 4 gaps
constexpr int LSTRB = 72;    // 64 cols + 2 gaps (max col' 67, pad to 72)
__device__ __forceinline__ int ldsCol(int c) { return c + 4 * (c >> 5); }

__global__ __launch_bounds__(256)
void ahat_gemm_kernel(const float* __restrict__ E, const float* __restrict__ ufin,
                      float* __restrict__ out) {
    __shared__ float uA[KC * LSTRA];
    __shared__ float eB[KC * LSTRB];
    const float* E3 = E + (size_t)Hn * Vn * Dn;

    const int tid   = threadIdx.x;
    const int tr    = tid & 15;
    const int tc    = tid >> 4;
    const int vbase = blockIdx.x * 64;

    const int f4 = tid & 7;        // k-float4 within chunk
    const int rr = tid >> 3;       // staging row 0..31

    float acc[8][4];
    #pragma unroll
    for (int i = 0; i < 8; ++i)
        #pragma unroll
        for (int j = 0; j < 4; ++j) acc[i][j] = 0.f;

    for (int kb = 0; kb < Dn; kb += KC) {
        #pragma unroll
        for (int i = 0; i < 4; ++i) {       // u rows
            int r = rr + 32 * i;
            float4 uv = *(const float4*)(ufin + (size_t)r * Dn + kb + f4 * 4);
            int col = ldsCol(r);
            uA[(f4 * 4 + 0) * LSTRA + col] = uv.x;
            uA[(f4 * 4 + 1) * LSTRA + col] = uv.y;
            uA[(f4 * 4 + 2) * LSTRA + col] = uv.z;
            uA[(f4 * 4 + 3) * LSTRA + col] = uv.w;
        }
        #pragma unroll
        for (int i = 0; i < 2; ++i) {       // E3 rows
            int r  = rr + 32 * i;
            int vg = vbase + r; if (vg > Vn - 1) vg = Vn - 1;
            float4 ev = *(const float4*)(E3 + (size_t)vg * Dn + kb + f4 * 4);
            int col = ldsCol(r);
            eB[(f4 * 4 + 0) * LSTRB + col] = ev.x;
            eB[(f4 * 4 + 1) * LSTRB + col] = ev.y;
            eB[(f4 * 4 + 2) * LSTRB + col] = ev.z;
            eB[(f4 * 4 + 3) * LSTRB + col] = ev.w;
        }
        __syncthreads();
        const int ca = ldsCol(tr * 8);
        const int cb = ldsCol(tc * 4);
        #pragma unroll 4
        for (int k = 0; k < KC; ++k) {
            float4 a0 = *(const float4*)&uA[k * LSTRA + ca];
            float4 a1 = *(const float4*)&uA[k * LSTRA + ca + 4];
            float4 b0 = *(const float4*)&eB[k * LSTRB + cb];
            float av[8] = {a0.x, a0.y, a0.z, a0.w, a1.x, a1.y, a1.z, a1.w};
            float bv[4] = {b0.x, b0.y, b0.z, b0.w};
            #pragma unroll
            for (int i = 0; i < 8; ++i)
                #pragma unroll
                for (int j = 0; j < 4; ++j)
                    acc[i][j] += av[i] * bv[j];
        }
        __syncthreads();
    }

    if (vbase + tc * 4 < Vn) {
        #pragma unroll
        for (int i = 0; i < 8; ++i) {
            int bb = tr * 8 + i;
            *(float4*)(out + (size_t)bb * Vn + vbase + tc * 4) =
                make_float4(acc[i][0], acc[i][1], acc[i][2], acc[i][3]);
        }
    }
}

// ===========================================================================
// Row softmax over V=50000 (fp32), float4. grid = B x 1024.
// ===========================================================================
__global__ __launch_bounds__(1024)
void softmax_kernel(const float* __restrict__ ahat, float* __restrict__ osm) {
    __shared__ float red[16];
    __shared__ float bc;

    int b    = blockIdx.x;
    int tid  = threadIdx.x;
    int wave = tid >> 6;
    int lane = tid & 63;

    const float4* row  = (const float4*)(ahat + (size_t)b * Vn);
    float4*       orow = (float4*)(osm + (size_t)b * Vn);
    constexpr int N4 = Vn / 4;

    float mx = -FLT_MAX;
    for (int v = tid; v < N4; v += 1024) {
        float4 x = row[v];
        mx = fmaxf(mx, fmaxf(fmaxf(x.x, x.y), fmaxf(x.z, x.w)));
    }
    #pragma unroll
    for (int off = 32; off; off >>= 1) mx = fmaxf(mx, __shfl_down(mx, off, 64));
    if (lane == 0) red[wave] = mx;
    __syncthreads();
    if (tid == 0) {
        float m = red[0];
        #pragma unroll
        for (int i = 1; i < 16; ++i) m = fmaxf(m, red[i]);
        bc = m;
    }
    __syncthreads();
    float rmax = bc;

    float sum = 0.f;
    for (int v = tid; v < N4; v += 1024) {
        float4 x = row[v];
        sum += expf(x.x - rmax) + expf(x.y - rmax) + expf(x.z - rmax) + expf(x.w - rmax);
    }
    #pragma unroll
    for (int off = 32; off; off >>= 1) sum += __shfl_down(sum, off, 64);
    if (lane == 0) red[wave] = sum;
    __syncthreads();
    if (tid == 0) {
        float s = 0.f;
        #pragma unroll
        for (int i = 0; i < 16; ++i) s += red[i];
        bc = s;
    }
    __syncthreads();
    float inv = 1.f / bc;

    for (int v = tid; v < N4; v += 1024) {
        float4 x = row[v];
        orow[v] = make_float4(expf(x.x - rmax) * inv, expf(x.y - rmax) * inv,
                              expf(x.z - rmax) * inv, expf(x.w - rmax) * inv);
    }
}

// ===========================================================================
extern "C" void kernel_launch(void* const* d_in, const int* in_sizes, int n_in,
                              void* d_out, int out_size, void* d_ws, size_t ws_size,
                              hipStream_t stream) {
    const int*   story = (const int*)d_in[0];
    const int*   query = (const int*)d_in[1];
    const float* E     = (const float*)d_in[2];
    const float* T     = (const float*)d_in[3];

    float* out  = (float*)d_out;
    float* ufin = out + (size_t)Bn * Vn;   // staged in dead second output half

    if (ws_size >= MSUM_ELEMS * sizeof(float)) {
        float* msum = (float*)d_ws;
        msum_kernel<<<(Hn + 1) * Bn * Mn / 8, 256, 0, stream>>>(story, E, T, msum);
        hops_kernel<<<Bn, 1024, 0, stream>>>(query, E, msum, ufin);
    } else {
        hops_fused_kernel<<<Bn, 1024, 0, stream>>>(story, query, E, T, ufin);
    }
    ahat_gemm_kernel<<<(Vn + 63) / 64, 256, 0, stream>>>(E, ufin, out);
    softmax_kernel<<<Bn, 1024, 0, stream>>>(out, out + (size_t)Bn * Vn);
}